// Round 1
// baseline (3081.994 us; speedup 1.0000x reference)
//
#include <hip/hip_runtime.h>

#define BN_EPS 1e-5f

// ---------------- edge scatter-add: agg[dst] += h[src] ----------------
// one edge handled by 16 threads, each doing a float4 gather + 4 atomics
__global__ __launch_bounds__(256) void scatter_add_k(
    const float* __restrict__ h, const int* __restrict__ src,
    const int* __restrict__ dst, float* __restrict__ agg, int E)
{
    long long idx = (long long)blockIdx.x * 256 + threadIdx.x;
    int e = (int)(idx >> 4);
    if (e >= E) return;
    int q = ((int)idx & 15) * 4;
    int s = src[e], d = dst[e];
    const float4 v = *(const float4*)(h + (size_t)s * 64 + q);
    float* o = agg + (size_t)d * 64 + q;
    atomicAdd(o + 0, v.x);
    atomicAdd(o + 1, v.y);
    atomicAdd(o + 2, v.z);
    atomicAdd(o + 3, v.w);
}

// ---------------- GEMM: out[r][c] = f(A)[r][:] @ W + bias ----------------
// MODE 0: a = A + B2 (h + agg);  MODE 1: a = relu(A*scale + shift)
// 128-row tile per block, W(64x64) + A tile in LDS (stride 68 to kill bank
// conflicts), each thread computes 8 rows x 4 cols. In-place safe (out==A).
template<int MODE>
__global__ __launch_bounds__(256) void gemm64_k(
    const float* __restrict__ A, const float* __restrict__ B2,
    const float* __restrict__ scale, const float* __restrict__ shift,
    const float* __restrict__ W, const float* __restrict__ bias,
    float* __restrict__ out, int nrows)
{
    __shared__ float sW[64 * 68];
    __shared__ float sA[128 * 68];
    const int tid = threadIdx.x;

    // stage W (4096 floats)
    for (int idx4 = tid; idx4 < 1024; idx4 += 256) {
        int r = idx4 >> 4, c4 = (idx4 & 15) * 4;
        *(float4*)(sW + r * 68 + c4) = *(const float4*)(W + idx4 * 4);
    }

    const int row0 = blockIdx.x * 128;
    const int rows = min(128, nrows - row0);

    // stage A tile with input transform
    for (int idx4 = tid; idx4 < rows * 16; idx4 += 256) {
        int r = idx4 >> 4, c4 = (idx4 & 15) * 4;
        float4 v = *(const float4*)(A + (size_t)(row0 + r) * 64 + c4);
        if (MODE == 0) {
            float4 u = *(const float4*)(B2 + (size_t)(row0 + r) * 64 + c4);
            v.x += u.x; v.y += u.y; v.z += u.z; v.w += u.w;
        } else {
            float4 sc = *(const float4*)(scale + c4);
            float4 sh = *(const float4*)(shift + c4);
            v.x = fmaxf(fmaf(v.x, sc.x, sh.x), 0.f);
            v.y = fmaxf(fmaf(v.y, sc.y, sh.y), 0.f);
            v.z = fmaxf(fmaf(v.z, sc.z, sh.z), 0.f);
            v.w = fmaxf(fmaf(v.w, sc.w, sh.w), 0.f);
        }
        *(float4*)(sA + r * 68 + c4) = v;
    }
    __syncthreads();

    const int cg = tid & 15, rg = tid >> 4;
    const int c0 = cg * 4;

    float acc[8][4];
    {
        float4 bv = *(const float4*)(bias + c0);
        #pragma unroll
        for (int i = 0; i < 8; i++) {
            acc[i][0] = bv.x; acc[i][1] = bv.y; acc[i][2] = bv.z; acc[i][3] = bv.w;
        }
    }

    #pragma unroll 2
    for (int k0 = 0; k0 < 64; k0 += 4) {
        float4 w0 = *(const float4*)(sW + (k0 + 0) * 68 + c0);
        float4 w1 = *(const float4*)(sW + (k0 + 1) * 68 + c0);
        float4 w2 = *(const float4*)(sW + (k0 + 2) * 68 + c0);
        float4 w3 = *(const float4*)(sW + (k0 + 3) * 68 + c0);
        #pragma unroll
        for (int i = 0; i < 8; i++) {
            float4 a = *(const float4*)(sA + (rg + 16 * i) * 68 + k0);
            acc[i][0] = fmaf(a.w, w3.x, fmaf(a.z, w2.x, fmaf(a.y, w1.x, fmaf(a.x, w0.x, acc[i][0]))));
            acc[i][1] = fmaf(a.w, w3.y, fmaf(a.z, w2.y, fmaf(a.y, w1.y, fmaf(a.x, w0.y, acc[i][1]))));
            acc[i][2] = fmaf(a.w, w3.z, fmaf(a.z, w2.z, fmaf(a.y, w1.z, fmaf(a.x, w0.z, acc[i][2]))));
            acc[i][3] = fmaf(a.w, w3.w, fmaf(a.z, w2.w, fmaf(a.y, w1.w, fmaf(a.x, w0.w, acc[i][3]))));
        }
    }

    #pragma unroll
    for (int i = 0; i < 8; i++) {
        int r = rg + 16 * i;
        if (r < rows) {
            float4 v = make_float4(acc[i][0], acc[i][1], acc[i][2], acc[i][3]);
            *(float4*)(out + (size_t)(row0 + r) * 64 + c0) = v;
        }
    }
}

// ---------------- BN column stats: stats[f]=sum, stats[64+f]=sumsq --------
__global__ __launch_bounds__(256) void bn_stats_k(
    const float* __restrict__ t, float* __restrict__ stats, int Nn)
{
    const int f = threadIdx.x & 63;
    const int slot = threadIdx.x >> 6;
    float s = 0.f, s2 = 0.f;
    for (int r = blockIdx.x * 4 + slot; r < Nn; r += gridDim.x * 4) {
        float v = t[(size_t)r * 64 + f];
        s += v;
        s2 = fmaf(v, v, s2);
    }
    __shared__ float red[512];
    red[threadIdx.x] = s;
    red[256 + threadIdx.x] = s2;
    __syncthreads();
    if (slot == 0) {
        s  = red[f] + red[64 + f] + red[128 + f] + red[192 + f];
        s2 = red[256 + f] + red[320 + f] + red[384 + f] + red[448 + f];
        atomicAdd(&stats[f], s);
        atomicAdd(&stats[64 + f], s2);
    }
}

// ---------------- BN finalize: scale/shift per feature ----------------
__global__ __launch_bounds__(64) void bn_finalize_k(
    const float* __restrict__ stats, const float* __restrict__ g,
    const float* __restrict__ be, float* __restrict__ sc,
    float* __restrict__ sh, float invN)
{
    const int f = threadIdx.x;
    float m = stats[f] * invN;
    float v = stats[64 + f] * invN - m * m;
    float s = g[f] * rsqrtf(v + BN_EPS);
    sc[f] = s;
    sh[f] = be[f] - m * s;
}

// ---------------- elementwise: out = relu(in*scale + shift) ----------------
__global__ __launch_bounds__(256) void affine_relu_k(
    const float* __restrict__ in, const float* __restrict__ sc,
    const float* __restrict__ sh, float* __restrict__ out, int total4)
{
    int i = blockIdx.x * 256 + threadIdx.x;
    if (i >= total4) return;
    float4 v = ((const float4*)in)[i];
    int c4 = i & 15;
    float4 s = ((const float4*)sc)[c4];
    float4 t = ((const float4*)sh)[c4];
    v.x = fmaxf(fmaf(v.x, s.x, t.x), 0.f);
    v.y = fmaxf(fmaf(v.y, s.y, t.y), 0.f);
    v.z = fmaxf(fmaf(v.z, s.z, t.z), 0.f);
    v.w = fmaxf(fmaf(v.w, s.w, t.w), 0.f);
    ((float4*)out)[i] = v;
}

// ---------------- pooled readout over sorted batch ----------------
// block g: binary-search node range, pool x/h1/h2, then out[g] = sum_l p_l@w_l + b_l
__global__ __launch_bounds__(256) void pool_readout_k(
    const float* __restrict__ x, const float* __restrict__ h1,
    const float* __restrict__ h2, const int* __restrict__ batch,
    const float* __restrict__ w0, const float* __restrict__ b0,
    const float* __restrict__ w1, const float* __restrict__ b1,
    const float* __restrict__ w2, const float* __restrict__ b2,
    float* __restrict__ out, int Nn)
{
    const int g = blockIdx.x;
    int lo = 0, hi = Nn;
    while (lo < hi) { int mid = (lo + hi) >> 1; if (batch[mid] < g) lo = mid + 1; else hi = mid; }
    const int start = lo;
    hi = Nn;
    while (lo < hi) { int mid = (lo + hi) >> 1; if (batch[mid] <= g) lo = mid + 1; else hi = mid; }
    const int end = lo;

    const int f = threadIdx.x & 63;
    const int w = threadIdx.x >> 6;
    float s0 = 0.f, s1 = 0.f, s2 = 0.f;
    for (int i = start + w; i < end; i += 4) {
        s0 += x [(size_t)i * 64 + f];
        s1 += h1[(size_t)i * 64 + f];
        s2 += h2[(size_t)i * 64 + f];
    }
    __shared__ float p[3][4][64];
    p[0][w][f] = s0; p[1][w][f] = s1; p[2][w][f] = s2;
    __syncthreads();
    if (threadIdx.x < 10) {
        const int c = threadIdx.x;
        float acc = b0[c] + b1[c] + b2[c];
        for (int k = 0; k < 64; k++) {
            float q0 = p[0][0][k] + p[0][1][k] + p[0][2][k] + p[0][3][k];
            float q1 = p[1][0][k] + p[1][1][k] + p[1][2][k] + p[1][3][k];
            float q2 = p[2][0][k] + p[2][1][k] + p[2][2][k] + p[2][3][k];
            acc = fmaf(q0, w0[k * 10 + c], acc);
            acc = fmaf(q1, w1[k * 10 + c], acc);
            acc = fmaf(q2, w2[k * 10 + c], acc);
        }
        out[(size_t)g * 10 + c] = acc;
    }
}

extern "C" void kernel_launch(void* const* d_in, const int* in_sizes, int n_in,
                              void* d_out, int out_size, void* d_ws, size_t ws_size,
                              hipStream_t stream)
{
    const float* x     = (const float*)d_in[0];
    const int*   edge  = (const int*)d_in[1];
    const int*   batch = (const int*)d_in[2];
    const int N = in_sizes[0] / 64;
    const int E = in_sizes[1] / 2;
    const int G = out_size / 10;
    const int* src = edge;
    const int* dst = edge + E;

    const float* c_w1[2]  = {(const float*)d_in[3],  (const float*)d_in[11]};
    const float* c_b1[2]  = {(const float*)d_in[4],  (const float*)d_in[12]};
    const float* c_g1[2]  = {(const float*)d_in[5],  (const float*)d_in[13]};
    const float* c_be1[2] = {(const float*)d_in[6],  (const float*)d_in[14]};
    const float* c_w2[2]  = {(const float*)d_in[7],  (const float*)d_in[15]};
    const float* c_b2[2]  = {(const float*)d_in[8],  (const float*)d_in[16]};
    const float* bn_g[2]  = {(const float*)d_in[9],  (const float*)d_in[17]};
    const float* bn_b[2]  = {(const float*)d_in[10], (const float*)d_in[18]};
    const float* lw[3]    = {(const float*)d_in[19], (const float*)d_in[21], (const float*)d_in[23]};
    const float* lb[3]    = {(const float*)d_in[20], (const float*)d_in[22], (const float*)d_in[24]};

    float* out = (float*)d_out;
    const size_t nh = (size_t)N * 64;
    float* agg   = (float*)d_ws;
    float* t     = agg + nh;
    float* h1    = t + nh;
    float* h2    = h1 + nh;
    float* stats = h2 + nh;   // 128 floats
    float* sc    = stats + 128;
    float* sh    = sc + 64;

    const float invN = 1.0f / (float)N;
    const int gemmGrid = (N + 127) / 128;
    const int scatGrid = (int)(((long long)E * 16 + 255) / 256);
    const int ewGrid   = (int)(((long long)N * 16 + 255) / 256);

    const float* hin = x;
    float* houts[2] = {h1, h2};
    for (int l = 0; l < 2; l++) {
        hipMemsetAsync(agg, 0, nh * sizeof(float), stream);
        scatter_add_k<<<scatGrid, 256, 0, stream>>>(hin, src, dst, agg, E);
        gemm64_k<0><<<gemmGrid, 256, 0, stream>>>(hin, agg, nullptr, nullptr,
                                                  c_w1[l], c_b1[l], t, N);
        hipMemsetAsync(stats, 0, 128 * sizeof(float), stream);
        bn_stats_k<<<512, 256, 0, stream>>>(t, stats, N);
        bn_finalize_k<<<1, 64, 0, stream>>>(stats, c_g1[l], c_be1[l], sc, sh, invN);
        gemm64_k<1><<<gemmGrid, 256, 0, stream>>>(t, nullptr, sc, sh,
                                                  c_w2[l], c_b2[l], t, N);  // in-place safe
        hipMemsetAsync(stats, 0, 128 * sizeof(float), stream);
        bn_stats_k<<<512, 256, 0, stream>>>(t, stats, N);
        bn_finalize_k<<<1, 64, 0, stream>>>(stats, bn_g[l], bn_b[l], sc, sh, invN);
        affine_relu_k<<<ewGrid, 256, 0, stream>>>(t, sc, sh, houts[l], (int)(nh / 4));
        hin = houts[l];
    }
    pool_readout_k<<<G, 256, 0, stream>>>(x, h1, h2, batch,
                                          lw[0], lb[0], lw[1], lb[1], lw[2], lb[2],
                                          out, N);
}

// Round 2
// 742.770 us; speedup vs baseline: 4.1493x; 4.1493x over previous
//
#include <hip/hip_runtime.h>

#define BN_EPS 1e-5f

// ================= CSR build (counting sort over dst) =================

__global__ __launch_bounds__(256) void hist_k(
    const int* __restrict__ dst, int* __restrict__ cnt, int E)
{
    int e = blockIdx.x * 256 + threadIdx.x;
    if (e < E) atomicAdd(&cnt[dst[e]], 1);
}

// per-1024-chunk sums
__global__ __launch_bounds__(256) void blocksum_k(
    const int* __restrict__ cnt, int* __restrict__ partials, int N)
{
    int base = blockIdx.x * 1024;
    int s = 0;
    for (int i = threadIdx.x; i < 1024; i += 256) {
        int idx = base + i;
        if (idx < N) s += cnt[idx];
    }
    __shared__ int red[256];
    red[threadIdx.x] = s;
    __syncthreads();
    for (int off = 128; off > 0; off >>= 1) {
        if (threadIdx.x < off) red[threadIdx.x] += red[threadIdx.x + off];
        __syncthreads();
    }
    if (threadIdx.x == 0) partials[blockIdx.x] = red[0];
}

// exclusive scan of partials (nb <= ~100, single thread is fine); writes total to rowptr[N]
__global__ void scanpartials_k(int* __restrict__ partials, int nb,
                               int* __restrict__ rowptr, int N)
{
    if (threadIdx.x == 0) {
        int acc = 0;
        for (int i = 0; i < nb; i++) { int v = partials[i]; partials[i] = acc; acc += v; }
        rowptr[N] = acc;
    }
}

// per-chunk exclusive scan + chunk offset -> rowptr
__global__ __launch_bounds__(256) void scatteroffsets_k(
    const int* __restrict__ cnt, const int* __restrict__ partials,
    int* __restrict__ rowptr, int N)
{
    const int t = threadIdx.x;
    const int base = blockIdx.x * 1024;
    int v[4], local = 0;
    #pragma unroll
    for (int j = 0; j < 4; j++) {
        int idx = base + t * 4 + j;
        v[j] = (idx < N) ? cnt[idx] : 0;
        local += v[j];
    }
    __shared__ int sc[256];
    sc[t] = local;
    __syncthreads();
    for (int off = 1; off < 256; off <<= 1) {
        int add = (t >= off) ? sc[t - off] : 0;
        __syncthreads();
        sc[t] += add;
        __syncthreads();
    }
    int excl = sc[t] - local + partials[blockIdx.x];
    #pragma unroll
    for (int j = 0; j < 4; j++) {
        int idx = base + t * 4 + j;
        if (idx < N) rowptr[idx] = excl;
        excl += v[j];
    }
}

__global__ __launch_bounds__(256) void fill_k(
    const int* __restrict__ src, const int* __restrict__ dst,
    int* __restrict__ cursor, int* __restrict__ adj, int E)
{
    int e = blockIdx.x * 256 + threadIdx.x;
    if (e < E) {
        int pos = atomicAdd(&cursor[dst[e]], 1);
        adj[pos] = src[e];
    }
}

// ========== aggregation: z[n] = h[n] + sum_{m in adj(n)} h[m] ==========
// one wave per node, lane = feature; 256B coalesced row gathers, no atomics
__global__ __launch_bounds__(256) void aggregate_k(
    const float* __restrict__ h, const int* __restrict__ rowptr,
    const int* __restrict__ adj, float* __restrict__ z, int N)
{
    int n = blockIdx.x * 4 + (threadIdx.x >> 6);
    if (n >= N) return;
    const int f = threadIdx.x & 63;
    const int b = rowptr[n], e = rowptr[n + 1];
    float s = h[(size_t)n * 64 + f];
    int i = b;
    for (; i + 2 <= e; i += 2) {
        int m0 = adj[i], m1 = adj[i + 1];
        float v0 = h[(size_t)m0 * 64 + f];
        float v1 = h[(size_t)m1 * 64 + f];
        s += v0 + v1;
    }
    if (i < e) s += h[(size_t)adj[i] * 64 + f];
    z[(size_t)n * 64 + f] = s;
}

// ---------------- GEMM: out[r][c] = f(A)[r][:] @ W + bias ----------------
// MODE 0: a = A;  MODE 1: a = relu(A*scale + shift)
// 128-row tile per block, W + A tile in LDS (stride 68), 8x4 accs/thread.
// In-place safe (out==A): tile fully staged before writes.
template<int MODE>
__global__ __launch_bounds__(256) void gemm64_k(
    const float* __restrict__ A,
    const float* __restrict__ scale, const float* __restrict__ shift,
    const float* __restrict__ W, const float* __restrict__ bias,
    float* __restrict__ out, int nrows)
{
    __shared__ float sW[64 * 68];
    __shared__ float sA[128 * 68];
    const int tid = threadIdx.x;

    for (int idx4 = tid; idx4 < 1024; idx4 += 256) {
        int r = idx4 >> 4, c4 = (idx4 & 15) * 4;
        *(float4*)(sW + r * 68 + c4) = *(const float4*)(W + idx4 * 4);
    }

    const int row0 = blockIdx.x * 128;
    const int rows = min(128, nrows - row0);

    for (int idx4 = tid; idx4 < rows * 16; idx4 += 256) {
        int r = idx4 >> 4, c4 = (idx4 & 15) * 4;
        float4 v = *(const float4*)(A + (size_t)(row0 + r) * 64 + c4);
        if (MODE == 1) {
            float4 sc = *(const float4*)(scale + c4);
            float4 sh = *(const float4*)(shift + c4);
            v.x = fmaxf(fmaf(v.x, sc.x, sh.x), 0.f);
            v.y = fmaxf(fmaf(v.y, sc.y, sh.y), 0.f);
            v.z = fmaxf(fmaf(v.z, sc.z, sh.z), 0.f);
            v.w = fmaxf(fmaf(v.w, sc.w, sh.w), 0.f);
        }
        *(float4*)(sA + r * 68 + c4) = v;
    }
    __syncthreads();

    const int cg = tid & 15, rg = tid >> 4;
    const int c0 = cg * 4;

    float acc[8][4];
    {
        float4 bv = *(const float4*)(bias + c0);
        #pragma unroll
        for (int i = 0; i < 8; i++) {
            acc[i][0] = bv.x; acc[i][1] = bv.y; acc[i][2] = bv.z; acc[i][3] = bv.w;
        }
    }

    #pragma unroll 2
    for (int k0 = 0; k0 < 64; k0 += 4) {
        float4 w0 = *(const float4*)(sW + (k0 + 0) * 68 + c0);
        float4 w1 = *(const float4*)(sW + (k0 + 1) * 68 + c0);
        float4 w2 = *(const float4*)(sW + (k0 + 2) * 68 + c0);
        float4 w3 = *(const float4*)(sW + (k0 + 3) * 68 + c0);
        #pragma unroll
        for (int i = 0; i < 8; i++) {
            float4 a = *(const float4*)(sA + (rg + 16 * i) * 68 + k0);
            acc[i][0] = fmaf(a.w, w3.x, fmaf(a.z, w2.x, fmaf(a.y, w1.x, fmaf(a.x, w0.x, acc[i][0]))));
            acc[i][1] = fmaf(a.w, w3.y, fmaf(a.z, w2.y, fmaf(a.y, w1.y, fmaf(a.x, w0.y, acc[i][1]))));
            acc[i][2] = fmaf(a.w, w3.z, fmaf(a.z, w2.z, fmaf(a.y, w1.z, fmaf(a.x, w0.z, acc[i][2]))));
            acc[i][3] = fmaf(a.w, w3.w, fmaf(a.z, w2.w, fmaf(a.y, w1.w, fmaf(a.x, w0.w, acc[i][3]))));
        }
    }

    #pragma unroll
    for (int i = 0; i < 8; i++) {
        int r = rg + 16 * i;
        if (r < rows) {
            float4 v = make_float4(acc[i][0], acc[i][1], acc[i][2], acc[i][3]);
            *(float4*)(out + (size_t)(row0 + r) * 64 + c0) = v;
        }
    }
}

// ---------------- BN column stats ----------------
__global__ __launch_bounds__(256) void bn_stats_k(
    const float* __restrict__ t, float* __restrict__ stats, int Nn)
{
    const int f = threadIdx.x & 63;
    const int slot = threadIdx.x >> 6;
    float s = 0.f, s2 = 0.f;
    for (int r = blockIdx.x * 4 + slot; r < Nn; r += gridDim.x * 4) {
        float v = t[(size_t)r * 64 + f];
        s += v;
        s2 = fmaf(v, v, s2);
    }
    __shared__ float red[512];
    red[threadIdx.x] = s;
    red[256 + threadIdx.x] = s2;
    __syncthreads();
    if (slot == 0) {
        s  = red[f] + red[64 + f] + red[128 + f] + red[192 + f];
        s2 = red[256 + f] + red[320 + f] + red[384 + f] + red[448 + f];
        atomicAdd(&stats[f], s);
        atomicAdd(&stats[64 + f], s2);
    }
}

__global__ __launch_bounds__(64) void bn_finalize_k(
    const float* __restrict__ stats, const float* __restrict__ g,
    const float* __restrict__ be, float* __restrict__ sc,
    float* __restrict__ sh, float invN)
{
    const int f = threadIdx.x;
    float m = stats[f] * invN;
    float v = stats[64 + f] * invN - m * m;
    float s = g[f] * rsqrtf(v + BN_EPS);
    sc[f] = s;
    sh[f] = be[f] - m * s;
}

__global__ __launch_bounds__(256) void affine_relu_k(
    const float* __restrict__ in, const float* __restrict__ sc,
    const float* __restrict__ sh, float* __restrict__ out, int total4)
{
    int i = blockIdx.x * 256 + threadIdx.x;
    if (i >= total4) return;
    float4 v = ((const float4*)in)[i];
    int c4 = i & 15;
    float4 s = ((const float4*)sc)[c4];
    float4 t = ((const float4*)sh)[c4];
    v.x = fmaxf(fmaf(v.x, s.x, t.x), 0.f);
    v.y = fmaxf(fmaf(v.y, s.y, t.y), 0.f);
    v.z = fmaxf(fmaf(v.z, s.z, t.z), 0.f);
    v.w = fmaxf(fmaf(v.w, s.w, t.w), 0.f);
    ((float4*)out)[i] = v;
}

// ---------------- pooled readout over sorted batch ----------------
__global__ __launch_bounds__(256) void pool_readout_k(
    const float* __restrict__ x, const float* __restrict__ h1,
    const float* __restrict__ h2, const int* __restrict__ batch,
    const float* __restrict__ w0, const float* __restrict__ b0,
    const float* __restrict__ w1, const float* __restrict__ b1,
    const float* __restrict__ w2, const float* __restrict__ b2,
    float* __restrict__ out, int Nn)
{
    const int g = blockIdx.x;
    int lo = 0, hi = Nn;
    while (lo < hi) { int mid = (lo + hi) >> 1; if (batch[mid] < g) lo = mid + 1; else hi = mid; }
    const int start = lo;
    hi = Nn;
    while (lo < hi) { int mid = (lo + hi) >> 1; if (batch[mid] <= g) lo = mid + 1; else hi = mid; }
    const int end = lo;

    const int f = threadIdx.x & 63;
    const int w = threadIdx.x >> 6;
    float s0 = 0.f, s1 = 0.f, s2 = 0.f;
    for (int i = start + w; i < end; i += 4) {
        s0 += x [(size_t)i * 64 + f];
        s1 += h1[(size_t)i * 64 + f];
        s2 += h2[(size_t)i * 64 + f];
    }
    __shared__ float p[3][4][64];
    p[0][w][f] = s0; p[1][w][f] = s1; p[2][w][f] = s2;
    __syncthreads();
    if (threadIdx.x < 10) {
        const int c = threadIdx.x;
        float acc = b0[c] + b1[c] + b2[c];
        for (int k = 0; k < 64; k++) {
            float q0 = p[0][0][k] + p[0][1][k] + p[0][2][k] + p[0][3][k];
            float q1 = p[1][0][k] + p[1][1][k] + p[1][2][k] + p[1][3][k];
            float q2 = p[2][0][k] + p[2][1][k] + p[2][2][k] + p[2][3][k];
            acc = fmaf(q0, w0[k * 10 + c], acc);
            acc = fmaf(q1, w1[k * 10 + c], acc);
            acc = fmaf(q2, w2[k * 10 + c], acc);
        }
        out[(size_t)g * 10 + c] = acc;
    }
}

extern "C" void kernel_launch(void* const* d_in, const int* in_sizes, int n_in,
                              void* d_out, int out_size, void* d_ws, size_t ws_size,
                              hipStream_t stream)
{
    const float* x     = (const float*)d_in[0];
    const int*   edge  = (const int*)d_in[1];
    const int*   batch = (const int*)d_in[2];
    const int N = in_sizes[0] / 64;
    const int E = in_sizes[1] / 2;
    const int G = out_size / 10;
    const int* src = edge;
    const int* dst = edge + E;

    const float* c_w1[2]  = {(const float*)d_in[3],  (const float*)d_in[11]};
    const float* c_b1[2]  = {(const float*)d_in[4],  (const float*)d_in[12]};
    const float* c_g1[2]  = {(const float*)d_in[5],  (const float*)d_in[13]};
    const float* c_be1[2] = {(const float*)d_in[6],  (const float*)d_in[14]};
    const float* c_w2[2]  = {(const float*)d_in[7],  (const float*)d_in[15]};
    const float* c_b2[2]  = {(const float*)d_in[8],  (const float*)d_in[16]};
    const float* bn_g[2]  = {(const float*)d_in[9],  (const float*)d_in[17]};
    const float* bn_b[2]  = {(const float*)d_in[10], (const float*)d_in[18]};
    const float* lw[3]    = {(const float*)d_in[19], (const float*)d_in[21], (const float*)d_in[23]};
    const float* lb[3]    = {(const float*)d_in[20], (const float*)d_in[22], (const float*)d_in[24]};

    float* out = (float*)d_out;
    const size_t nh = (size_t)N * 64;

    // workspace layout
    float* z     = (float*)d_ws;          // nh floats (z / gemm buffer, in-place)
    float* h1    = z + nh;                // nh
    float* h2    = h1 + nh;               // nh
    float* stats = h2 + nh;               // 128
    float* sc    = stats + 128;           // 64
    float* sh    = sc + 64;               // 64
    int*   cnt      = (int*)(sh + 64);    // N
    int*   rowptr   = cnt + N;            // N+1
    int*   cursor   = rowptr + N + 1;     // N
    int*   partials = cursor + N;         // nb+1
    const int nb = (N + 1023) / 1024;
    int*   adj      = partials + nb + 1;  // E

    const float invN = 1.0f / (float)N;
    const int gemmGrid = (N + 127) / 128;
    const int edgeGrid = (E + 255) / 256;
    const int aggGrid  = (N + 3) / 4;
    const int ewGrid   = (int)(((long long)N * 16 + 255) / 256);

    // ---- CSR build (once, reused by both layers) ----
    hipMemsetAsync(cnt, 0, (size_t)N * sizeof(int), stream);
    hist_k<<<edgeGrid, 256, 0, stream>>>(dst, cnt, E);
    blocksum_k<<<nb, 256, 0, stream>>>(cnt, partials, N);
    scanpartials_k<<<1, 64, 0, stream>>>(partials, nb, rowptr, N);
    scatteroffsets_k<<<nb, 256, 0, stream>>>(cnt, partials, rowptr, N);
    hipMemcpyAsync(cursor, rowptr, (size_t)N * sizeof(int),
                   hipMemcpyDeviceToDevice, stream);
    fill_k<<<edgeGrid, 256, 0, stream>>>(src, dst, cursor, adj, E);

    const float* hin = x;
    float* houts[2] = {h1, h2};
    for (int l = 0; l < 2; l++) {
        aggregate_k<<<aggGrid, 256, 0, stream>>>(hin, rowptr, adj, z, N);
        gemm64_k<0><<<gemmGrid, 256, 0, stream>>>(z, nullptr, nullptr,
                                                  c_w1[l], c_b1[l], z, N);
        hipMemsetAsync(stats, 0, 128 * sizeof(float), stream);
        bn_stats_k<<<512, 256, 0, stream>>>(z, stats, N);
        bn_finalize_k<<<1, 64, 0, stream>>>(stats, c_g1[l], c_be1[l], sc, sh, invN);
        gemm64_k<1><<<gemmGrid, 256, 0, stream>>>(z, sc, sh,
                                                  c_w2[l], c_b2[l], z, N);
        hipMemsetAsync(stats, 0, 128 * sizeof(float), stream);
        bn_stats_k<<<512, 256, 0, stream>>>(z, stats, N);
        bn_finalize_k<<<1, 64, 0, stream>>>(stats, bn_g[l], bn_b[l], sc, sh, invN);
        affine_relu_k<<<ewGrid, 256, 0, stream>>>(z, sc, sh, houts[l], (int)(nh / 4));
        hin = houts[l];
    }
    pool_readout_k<<<G, 256, 0, stream>>>(x, h1, h2, batch,
                                          lw[0], lb[0], lw[1], lb[1], lw[2], lb[2],
                                          out, N);
}

// Round 3
// 483.619 us; speedup vs baseline: 6.3728x; 1.5359x over previous
//
#include <hip/hip_runtime.h>
#include <hip/hip_bf16.h>

#define BN_EPS 1e-5f
#define NBMAX 512      // max buckets (N/256)
#define CHUNK 4096     // edges per binning block
#define CAPC  6144     // per-bucket LDS staging capacity (avg ~4096)

typedef __hip_bfloat16 bf16;

// ================= CSR build: two-level bucket sort over dst =================

// pass A: per-bucket edge counts (LDS hist per block, one atomic per bucket per block)
__global__ __launch_bounds__(256) void bincount_k(
    const int* __restrict__ dst, int* __restrict__ btot, int E, int NB)
{
    __shared__ int h[NBMAX];
    for (int i = threadIdx.x; i < NB; i += 256) h[i] = 0;
    __syncthreads();
    const int base = blockIdx.x * CHUNK;
    const int lim = min(CHUNK, E - base);
    for (int i = threadIdx.x; i < lim; i += 256)
        atomicAdd(&h[dst[base + i] >> 8], 1);
    __syncthreads();
    for (int i = threadIdx.x; i < NB; i += 256)
        if (h[i]) atomicAdd(&btot[i], h[i]);
}

// scan bucket totals -> bbase (exclusive), init bcur, set rowptr[N]=E
__global__ __launch_bounds__(256) void bucketscan_k(
    const int* __restrict__ btot, int* __restrict__ bbase,
    int* __restrict__ bcur, int* __restrict__ rowptr, int NB, int N, int E)
{
    __shared__ int s[256];
    const int t = threadIdx.x;
    int v0 = (2 * t     < NB) ? btot[2 * t]     : 0;
    int v1 = (2 * t + 1 < NB) ? btot[2 * t + 1] : 0;
    s[t] = v0 + v1;
    __syncthreads();
    for (int off = 1; off < 256; off <<= 1) {
        int a = (t >= off) ? s[t - off] : 0;
        __syncthreads();
        s[t] += a;
        __syncthreads();
    }
    int excl = s[t] - (v0 + v1);
    if (2 * t < NB)     { bbase[2 * t] = excl;          bcur[2 * t] = excl; }
    if (2 * t + 1 < NB) { bbase[2 * t + 1] = excl + v0; bcur[2 * t + 1] = excl + v0; }
    if (t == 0) { bbase[NB] = E; rowptr[N] = E; }
}

// pass B: scatter packed (src<<8 | dst&255) into bucket-contiguous tmp
__global__ __launch_bounds__(256) void binscatter_k(
    const int* __restrict__ src, const int* __restrict__ dst,
    int* __restrict__ bcur, int* __restrict__ tmp, int E, int NB)
{
    __shared__ int hist[NBMAX];
    __shared__ int loff[NBMAX];
    __shared__ int gb[NBMAX];
    __shared__ int lcur[NBMAX];
    __shared__ int staged[CHUNK];
    __shared__ unsigned short sb[CHUNK];
    __shared__ int ssc[256];
    const int t = threadIdx.x;
    for (int i = t; i < NB; i += 256) { hist[i] = 0; lcur[i] = 0; }
    __syncthreads();
    const int base = blockIdx.x * CHUNK;
    const int lim = min(CHUNK, E - base);
    int myb[16], myw[16];
    int cnt = 0;
    for (int i = t; i < lim; i += 256) {
        int d = dst[base + i];
        int s_ = src[base + i];
        int b = d >> 8;
        myb[cnt] = b;
        myw[cnt] = (s_ << 8) | (d & 255);
        cnt++;
        atomicAdd(&hist[b], 1);
    }
    __syncthreads();
    // exclusive scan of hist (2 entries/thread)
    int v0 = (2 * t     < NB) ? hist[2 * t]     : 0;
    int v1 = (2 * t + 1 < NB) ? hist[2 * t + 1] : 0;
    ssc[t] = v0 + v1;
    __syncthreads();
    for (int off = 1; off < 256; off <<= 1) {
        int a = (t >= off) ? ssc[t - off] : 0;
        __syncthreads();
        ssc[t] += a;
        __syncthreads();
    }
    int excl = ssc[t] - (v0 + v1);
    if (2 * t < NB)     loff[2 * t] = excl;
    if (2 * t + 1 < NB) loff[2 * t + 1] = excl + v0;
    __syncthreads();
    // reserve global ranges (one atomic per non-empty bucket)
    for (int b = t; b < NB; b += 256)
        if (hist[b] > 0) gb[b] = atomicAdd(&bcur[b], hist[b]);
    // group edges by bucket in LDS
    for (int i = 0; i < cnt; i++) {
        int b = myb[i];
        int p = loff[b] + atomicAdd(&lcur[b], 1);
        staged[p] = myw[i];
        sb[p] = (unsigned short)b;
    }
    __syncthreads();
    // write out: contiguous runs per bucket
    for (int i = t; i < lim; i += 256) {
        int b = sb[i];
        tmp[gb[b] + (i - loff[b])] = staged[i];
    }
}

// pass C: per bucket (256 nodes): counting sort in LDS -> rowptr + coalesced adj
__global__ __launch_bounds__(256) void csr_k(
    const int* __restrict__ bbase, const int* __restrict__ tmp,
    int* __restrict__ rowptr, int* __restrict__ adj, int N)
{
    __shared__ int hist[256], pfx[256], cur[256], ssc[256];
    __shared__ int sadj[CAPC];
    const int b = blockIdx.x, t = threadIdx.x;
    const int lo = bbase[b], hi = bbase[b + 1];
    const int cnt = hi - lo;
    hist[t] = 0; cur[t] = 0;
    __syncthreads();
    for (int i = t; i < cnt; i += 256)
        atomicAdd(&hist[tmp[lo + i] & 255], 1);
    __syncthreads();
    int v = hist[t];
    ssc[t] = v;
    __syncthreads();
    for (int off = 1; off < 256; off <<= 1) {
        int a = (t >= off) ? ssc[t - off] : 0;
        __syncthreads();
        ssc[t] += a;
        __syncthreads();
    }
    pfx[t] = ssc[t] - v;
    const int node = b * 256 + t;
    if (node < N) rowptr[node] = lo + pfx[t];
    __syncthreads();
    if (cnt <= CAPC) {
        for (int i = t; i < cnt; i += 256) {
            int w = tmp[lo + i];
            int d = w & 255;
            int p = pfx[d] + atomicAdd(&cur[d], 1);
            sadj[p] = w >> 8;
        }
        __syncthreads();
        for (int i = t; i < cnt; i += 256) adj[lo + i] = sadj[i];
    } else {  // overflow fallback (never expected at these sizes)
        for (int i = t; i < cnt; i += 256) {
            int w = tmp[lo + i];
            int d = w & 255;
            int p = pfx[d] + atomicAdd(&cur[d], 1);
            adj[lo + p] = w >> 8;
        }
    }
}

// ========== aggregation: z[n] = h[n] + sum_{m in adj(n)} h[m], bf16 in / f32 out ==========
__global__ __launch_bounds__(256) void aggregate_k(
    const bf16* __restrict__ h, const int* __restrict__ rowptr,
    const int* __restrict__ adj, float* __restrict__ z, int N)
{
    int n = blockIdx.x * 4 + (threadIdx.x >> 6);
    if (n >= N) return;
    const int f = threadIdx.x & 63;
    const int b = rowptr[n], e = rowptr[n + 1];
    float s = __bfloat162float(h[(size_t)n * 64 + f]);
    int i = b;
    for (; i + 4 <= e; i += 4) {
        int m0 = adj[i], m1 = adj[i + 1], m2 = adj[i + 2], m3 = adj[i + 3];
        float v0 = __bfloat162float(h[(size_t)m0 * 64 + f]);
        float v1 = __bfloat162float(h[(size_t)m1 * 64 + f]);
        float v2 = __bfloat162float(h[(size_t)m2 * 64 + f]);
        float v3 = __bfloat162float(h[(size_t)m3 * 64 + f]);
        s += (v0 + v1) + (v2 + v3);
    }
    for (; i < e; i++) s += __bfloat162float(h[(size_t)adj[i] * 64 + f]);
    z[(size_t)n * 64 + f] = s;
}

// ---------------- GEMM + fused BN-stats epilogue ----------------
// MODE 0: a = A;  MODE 1: a = relu(A*scale + shift). In-place safe (out==A).
// stats[0:64]=col sums, stats[64:128]=col sumsq (atomicAdd per block).
template<int MODE>
__global__ __launch_bounds__(256) void gemm64_k(
    const float* __restrict__ A,
    const float* __restrict__ scale, const float* __restrict__ shift,
    const float* __restrict__ W, const float* __restrict__ bias,
    float* __restrict__ out, float* __restrict__ stats, int nrows)
{
    __shared__ float sW[64 * 68];
    __shared__ float sA[128 * 68];
    const int tid = threadIdx.x;

    for (int idx4 = tid; idx4 < 1024; idx4 += 256) {
        int r = idx4 >> 4, c4 = (idx4 & 15) * 4;
        *(float4*)(sW + r * 68 + c4) = *(const float4*)(W + idx4 * 4);
    }

    const int row0 = blockIdx.x * 128;
    const int rows = min(128, nrows - row0);

    for (int idx4 = tid; idx4 < rows * 16; idx4 += 256) {
        int r = idx4 >> 4, c4 = (idx4 & 15) * 4;
        float4 v = *(const float4*)(A + (size_t)(row0 + r) * 64 + c4);
        if (MODE == 1) {
            float4 sc = *(const float4*)(scale + c4);
            float4 sh = *(const float4*)(shift + c4);
            v.x = fmaxf(fmaf(v.x, sc.x, sh.x), 0.f);
            v.y = fmaxf(fmaf(v.y, sc.y, sh.y), 0.f);
            v.z = fmaxf(fmaf(v.z, sc.z, sh.z), 0.f);
            v.w = fmaxf(fmaf(v.w, sc.w, sh.w), 0.f);
        }
        *(float4*)(sA + r * 68 + c4) = v;
    }
    __syncthreads();

    const int cg = tid & 15, rg = tid >> 4;
    const int c0 = cg * 4;

    float acc[8][4];
    {
        float4 bv = *(const float4*)(bias + c0);
        #pragma unroll
        for (int i = 0; i < 8; i++) {
            acc[i][0] = bv.x; acc[i][1] = bv.y; acc[i][2] = bv.z; acc[i][3] = bv.w;
        }
    }

    #pragma unroll 2
    for (int k0 = 0; k0 < 64; k0 += 4) {
        float4 w0 = *(const float4*)(sW + (k0 + 0) * 68 + c0);
        float4 w1 = *(const float4*)(sW + (k0 + 1) * 68 + c0);
        float4 w2 = *(const float4*)(sW + (k0 + 2) * 68 + c0);
        float4 w3 = *(const float4*)(sW + (k0 + 3) * 68 + c0);
        #pragma unroll
        for (int i = 0; i < 8; i++) {
            float4 a = *(const float4*)(sA + (rg + 16 * i) * 68 + k0);
            acc[i][0] = fmaf(a.w, w3.x, fmaf(a.z, w2.x, fmaf(a.y, w1.x, fmaf(a.x, w0.x, acc[i][0]))));
            acc[i][1] = fmaf(a.w, w3.y, fmaf(a.z, w2.y, fmaf(a.y, w1.y, fmaf(a.x, w0.y, acc[i][1]))));
            acc[i][2] = fmaf(a.w, w3.z, fmaf(a.z, w2.z, fmaf(a.y, w1.z, fmaf(a.x, w0.z, acc[i][2]))));
            acc[i][3] = fmaf(a.w, w3.w, fmaf(a.z, w2.w, fmaf(a.y, w1.w, fmaf(a.x, w0.w, acc[i][3]))));
        }
    }

    float csum[4] = {0.f, 0.f, 0.f, 0.f}, csq[4] = {0.f, 0.f, 0.f, 0.f};
    #pragma unroll
    for (int i = 0; i < 8; i++) {
        int r = rg + 16 * i;
        if (r < rows) {
            float4 v = make_float4(acc[i][0], acc[i][1], acc[i][2], acc[i][3]);
            *(float4*)(out + (size_t)(row0 + r) * 64 + c0) = v;
            #pragma unroll
            for (int j = 0; j < 4; j++) {
                csum[j] += acc[i][j];
                csq[j] = fmaf(acc[i][j], acc[i][j], csq[j]);
            }
        }
    }

    // block-level column reduction into stats (reuse sA as scratch)
    __syncthreads();
    #pragma unroll
    for (int j = 0; j < 4; j++) {
        sA[rg * 64 + c0 + j] = csum[j];
        sA[1024 + rg * 64 + c0 + j] = csq[j];
    }
    __syncthreads();
    if (tid < 128) {
        const int c = tid & 63, which = tid >> 6;
        const float* p = sA + which * 1024 + c;
        float a = 0.f;
        #pragma unroll
        for (int g2 = 0; g2 < 16; g2++) a += p[g2 * 64];
        atomicAdd(&stats[which * 64 + c], a);
    }
}

__global__ __launch_bounds__(64) void bn_finalize_k(
    const float* __restrict__ stats, const float* __restrict__ g,
    const float* __restrict__ be, float* __restrict__ sc,
    float* __restrict__ sh, float invN)
{
    const int f = threadIdx.x;
    float m = stats[f] * invN;
    float v = stats[64 + f] * invN - m * m;
    float s = g[f] * rsqrtf(v + BN_EPS);
    sc[f] = s;
    sh[f] = be[f] - m * s;
}

// f32 -> bf16 cast (4 elems/thread)
__global__ __launch_bounds__(256) void cast_k(
    const float* __restrict__ in, bf16* __restrict__ out, int total4)
{
    int i = blockIdx.x * 256 + threadIdx.x;
    if (i >= total4) return;
    float4 v = ((const float4*)in)[i];
    union { ushort4 u; bf16 b[4]; } p;
    p.b[0] = __float2bfloat16(v.x);
    p.b[1] = __float2bfloat16(v.y);
    p.b[2] = __float2bfloat16(v.z);
    p.b[3] = __float2bfloat16(v.w);
    ((ushort4*)out)[i] = p.u;
}

// relu(affine(z)) -> bf16
__global__ __launch_bounds__(256) void affine_relu_bf16_k(
    const float* __restrict__ in, const float* __restrict__ sc,
    const float* __restrict__ sh, bf16* __restrict__ out, int total4)
{
    int i = blockIdx.x * 256 + threadIdx.x;
    if (i >= total4) return;
    float4 v = ((const float4*)in)[i];
    int c4 = i & 15;
    float4 s = ((const float4*)sc)[c4];
    float4 t = ((const float4*)sh)[c4];
    union { ushort4 u; bf16 b[4]; } p;
    p.b[0] = __float2bfloat16(fmaxf(fmaf(v.x, s.x, t.x), 0.f));
    p.b[1] = __float2bfloat16(fmaxf(fmaf(v.y, s.y, t.y), 0.f));
    p.b[2] = __float2bfloat16(fmaxf(fmaf(v.z, s.z, t.z), 0.f));
    p.b[3] = __float2bfloat16(fmaxf(fmaf(v.w, s.w, t.w), 0.f));
    ((ushort4*)out)[i] = p.u;
}

// ---------------- pooled readout; h2 = relu(affine(z)) applied on the fly ----------------
__global__ __launch_bounds__(256) void pool_readout_k(
    const bf16* __restrict__ xb, const bf16* __restrict__ h1b,
    const float* __restrict__ z, const float* __restrict__ sc2,
    const float* __restrict__ sh2, const int* __restrict__ batch,
    const float* __restrict__ w0, const float* __restrict__ b0,
    const float* __restrict__ w1, const float* __restrict__ b1,
    const float* __restrict__ w2, const float* __restrict__ b2,
    float* __restrict__ out, int Nn)
{
    const int g = blockIdx.x;
    int lo = 0, hi = Nn;
    while (lo < hi) { int mid = (lo + hi) >> 1; if (batch[mid] < g) lo = mid + 1; else hi = mid; }
    const int start = lo;
    hi = Nn;
    while (lo < hi) { int mid = (lo + hi) >> 1; if (batch[mid] <= g) lo = mid + 1; else hi = mid; }
    const int end = lo;

    const int f = threadIdx.x & 63;
    const int w = threadIdx.x >> 6;
    const float scf = sc2[f], shf = sh2[f];
    float s0 = 0.f, s1 = 0.f, s2 = 0.f;
    for (int i = start + w; i < end; i += 4) {
        s0 += __bfloat162float(xb [(size_t)i * 64 + f]);
        s1 += __bfloat162float(h1b[(size_t)i * 64 + f]);
        s2 += fmaxf(fmaf(z[(size_t)i * 64 + f], scf, shf), 0.f);
    }
    __shared__ float p[3][4][64];
    p[0][w][f] = s0; p[1][w][f] = s1; p[2][w][f] = s2;
    __syncthreads();
    if (threadIdx.x < 10) {
        const int c = threadIdx.x;
        float acc = b0[c] + b1[c] + b2[c];
        for (int k = 0; k < 64; k++) {
            float q0 = p[0][0][k] + p[0][1][k] + p[0][2][k] + p[0][3][k];
            float q1 = p[1][0][k] + p[1][1][k] + p[1][2][k] + p[1][3][k];
            float q2 = p[2][0][k] + p[2][1][k] + p[2][2][k] + p[2][3][k];
            acc = fmaf(q0, w0[k * 10 + c], acc);
            acc = fmaf(q1, w1[k * 10 + c], acc);
            acc = fmaf(q2, w2[k * 10 + c], acc);
        }
        out[(size_t)g * 10 + c] = acc;
    }
}

extern "C" void kernel_launch(void* const* d_in, const int* in_sizes, int n_in,
                              void* d_out, int out_size, void* d_ws, size_t ws_size,
                              hipStream_t stream)
{
    const float* x     = (const float*)d_in[0];
    const int*   edge  = (const int*)d_in[1];
    const int*   batch = (const int*)d_in[2];
    const int N = in_sizes[0] / 64;
    const int E = in_sizes[1] / 2;
    const int G = out_size / 10;
    const int* src = edge;
    const int* dst = edge + E;
    const int NB = (N + 255) / 256;

    const float* c_w1[2]  = {(const float*)d_in[3],  (const float*)d_in[11]};
    const float* c_b1[2]  = {(const float*)d_in[4],  (const float*)d_in[12]};
    const float* c_g1[2]  = {(const float*)d_in[5],  (const float*)d_in[13]};
    const float* c_be1[2] = {(const float*)d_in[6],  (const float*)d_in[14]};
    const float* c_w2[2]  = {(const float*)d_in[7],  (const float*)d_in[15]};
    const float* c_b2[2]  = {(const float*)d_in[8],  (const float*)d_in[16]};
    const float* bn_g[2]  = {(const float*)d_in[9],  (const float*)d_in[17]};
    const float* bn_b[2]  = {(const float*)d_in[10], (const float*)d_in[18]};
    const float* lw[3]    = {(const float*)d_in[19], (const float*)d_in[21], (const float*)d_in[23]};
    const float* lb[3]    = {(const float*)d_in[20], (const float*)d_in[22], (const float*)d_in[24]};

    float* out = (float*)d_out;
    const size_t nh = (size_t)N * 64;

    // workspace layout (16B-aligned chunks, large-first)
    float* z     = (float*)d_ws;               // nh f32
    bf16*  xb    = (bf16*)(z + nh);            // nh bf16
    bf16*  h1b   = xb + nh;                    // nh bf16
    float* stats = (float*)(h1b + nh);         // 4 slots x 128
    float* sc    = stats + 512;                // 64
    float* sh    = sc + 64;                    // 64
    int*   rowptr   = (int*)(sh + 64);         // N+1
    int*   adj      = rowptr + N + 1;          // E
    int*   tmp      = adj + E;                 // E
    int*   btot     = tmp + E;                 // NB+1
    int*   bbase    = btot + NB + 1;           // NB+1
    int*   bcur     = bbase + NB + 1;          // NB

    const float invN = 1.0f / (float)N;
    const int gemmGrid = (N + 127) / 128;
    const int binGrid  = (E + CHUNK - 1) / CHUNK;
    const int aggGrid  = (N + 3) / 4;
    const int ewGrid   = (int)((nh / 4 + 255) / 256);

    // zero accumulators (ws is poisoned every call)
    hipMemsetAsync(btot, 0, (size_t)(NB + 1) * sizeof(int), stream);
    hipMemsetAsync(stats, 0, 512 * sizeof(float), stream);

    // ---- CSR build ----
    bincount_k<<<binGrid, 256, 0, stream>>>(dst, btot, E, NB);
    bucketscan_k<<<1, 256, 0, stream>>>(btot, bbase, bcur, rowptr, NB, N, E);
    binscatter_k<<<binGrid, 256, 0, stream>>>(src, dst, bcur, tmp, E, NB);
    csr_k<<<NB, 256, 0, stream>>>(bbase, tmp, rowptr, adj, N);

    // ---- x -> bf16 (overlaps with CSR build on the same stream order) ----
    cast_k<<<ewGrid, 256, 0, stream>>>(x, xb, (int)(nh / 4));

    // ---- layer 0 ----
    aggregate_k<<<aggGrid, 256, 0, stream>>>(xb, rowptr, adj, z, N);
    gemm64_k<0><<<gemmGrid, 256, 0, stream>>>(z, nullptr, nullptr,
                                              c_w1[0], c_b1[0], z, stats, N);
    bn_finalize_k<<<1, 64, 0, stream>>>(stats, c_g1[0], c_be1[0], sc, sh, invN);
    gemm64_k<1><<<gemmGrid, 256, 0, stream>>>(z, sc, sh,
                                              c_w2[0], c_b2[0], z, stats + 128, N);
    bn_finalize_k<<<1, 64, 0, stream>>>(stats + 128, bn_g[0], bn_b[0], sc, sh, invN);
    affine_relu_bf16_k<<<ewGrid, 256, 0, stream>>>(z, sc, sh, h1b, (int)(nh / 4));

    // ---- layer 1 ----
    aggregate_k<<<aggGrid, 256, 0, stream>>>(h1b, rowptr, adj, z, N);
    gemm64_k<0><<<gemmGrid, 256, 0, stream>>>(z, nullptr, nullptr,
                                              c_w1[1], c_b1[1], z, stats + 256, N);
    bn_finalize_k<<<1, 64, 0, stream>>>(stats + 256, c_g1[1], c_be1[1], sc, sh, invN);
    gemm64_k<1><<<gemmGrid, 256, 0, stream>>>(z, sc, sh,
                                              c_w2[1], c_b2[1], z, stats + 384, N);
    bn_finalize_k<<<1, 64, 0, stream>>>(stats + 384, bn_g[1], bn_b[1], sc, sh, invN);

    // ---- pooled readout (h2 affine+relu fused) ----
    pool_readout_k<<<G, 256, 0, stream>>>(xb, h1b, z, sc, sh, batch,
                                          lw[0], lb[0], lw[1], lb[1], lw[2], lb[2],
                                          out, N);
}

// Round 4
// 460.624 us; speedup vs baseline: 6.6909x; 1.0499x over previous
//
#include <hip/hip_runtime.h>
#include <hip/hip_bf16.h>

#define BN_EPS 1e-5f
#define NBMAX 512      // max buckets (N/256)
#define CHUNK 4096     // edges per binning block
#define CAPC  6144     // per-bucket LDS staging capacity (avg ~4096)

typedef __hip_bfloat16 bf16;

__device__ __forceinline__ float b2f(bf16 v) { return __bfloat162float(v); }
__device__ __forceinline__ bf16 f2b(float v) { return __float2bfloat16(v); }

// ================= CSR build: two-level bucket sort over dst =================

__global__ __launch_bounds__(256) void bincount_k(
    const int* __restrict__ dst, int* __restrict__ btot, int E, int NB)
{
    __shared__ int h[NBMAX];
    for (int i = threadIdx.x; i < NB; i += 256) h[i] = 0;
    __syncthreads();
    const int base = blockIdx.x * CHUNK;
    const int lim = min(CHUNK, E - base);
    for (int i = threadIdx.x; i < lim; i += 256)
        atomicAdd(&h[dst[base + i] >> 8], 1);
    __syncthreads();
    for (int i = threadIdx.x; i < NB; i += 256)
        if (h[i]) atomicAdd(&btot[i], h[i]);
}

__global__ __launch_bounds__(256) void bucketscan_k(
    const int* __restrict__ btot, int* __restrict__ bbase,
    int* __restrict__ bcur, int* __restrict__ rowptr, int NB, int N, int E)
{
    __shared__ int s[256];
    const int t = threadIdx.x;
    int v0 = (2 * t     < NB) ? btot[2 * t]     : 0;
    int v1 = (2 * t + 1 < NB) ? btot[2 * t + 1] : 0;
    s[t] = v0 + v1;
    __syncthreads();
    for (int off = 1; off < 256; off <<= 1) {
        int a = (t >= off) ? s[t - off] : 0;
        __syncthreads();
        s[t] += a;
        __syncthreads();
    }
    int excl = s[t] - (v0 + v1);
    if (2 * t < NB)     { bbase[2 * t] = excl;          bcur[2 * t] = excl; }
    if (2 * t + 1 < NB) { bbase[2 * t + 1] = excl + v0; bcur[2 * t + 1] = excl + v0; }
    if (t == 0) { bbase[NB] = E; rowptr[N] = E; }
}

__global__ __launch_bounds__(256) void binscatter_k(
    const int* __restrict__ src, const int* __restrict__ dst,
    int* __restrict__ bcur, int* __restrict__ tmp, int E, int NB)
{
    __shared__ int hist[NBMAX];
    __shared__ int loff[NBMAX];
    __shared__ int gb[NBMAX];
    __shared__ int lcur[NBMAX];
    __shared__ int staged[CHUNK];
    __shared__ unsigned short sb[CHUNK];
    __shared__ int ssc[256];
    const int t = threadIdx.x;
    for (int i = t; i < NB; i += 256) { hist[i] = 0; lcur[i] = 0; }
    __syncthreads();
    const int base = blockIdx.x * CHUNK;
    const int lim = min(CHUNK, E - base);
    int myb[16], myw[16];
    int cnt = 0;
    for (int i = t; i < lim; i += 256) {
        int d = dst[base + i];
        int s_ = src[base + i];
        int b = d >> 8;
        myb[cnt] = b;
        myw[cnt] = (s_ << 8) | (d & 255);
        cnt++;
        atomicAdd(&hist[b], 1);
    }
    __syncthreads();
    int v0 = (2 * t     < NB) ? hist[2 * t]     : 0;
    int v1 = (2 * t + 1 < NB) ? hist[2 * t + 1] : 0;
    ssc[t] = v0 + v1;
    __syncthreads();
    for (int off = 1; off < 256; off <<= 1) {
        int a = (t >= off) ? ssc[t - off] : 0;
        __syncthreads();
        ssc[t] += a;
        __syncthreads();
    }
    int excl = ssc[t] - (v0 + v1);
    if (2 * t < NB)     loff[2 * t] = excl;
    if (2 * t + 1 < NB) loff[2 * t + 1] = excl + v0;
    __syncthreads();
    for (int b = t; b < NB; b += 256)
        if (hist[b] > 0) gb[b] = atomicAdd(&bcur[b], hist[b]);
    for (int i = 0; i < cnt; i++) {
        int b = myb[i];
        int p = loff[b] + atomicAdd(&lcur[b], 1);
        staged[p] = myw[i];
        sb[p] = (unsigned short)b;
    }
    __syncthreads();
    for (int i = t; i < lim; i += 256) {
        int b = sb[i];
        tmp[gb[b] + (i - loff[b])] = staged[i];
    }
}

__global__ __launch_bounds__(256) void csr_k(
    const int* __restrict__ bbase, const int* __restrict__ tmp,
    int* __restrict__ rowptr, int* __restrict__ adj, int N)
{
    __shared__ int hist[256], pfx[256], cur[256], ssc[256];
    __shared__ int sadj[CAPC];
    const int b = blockIdx.x, t = threadIdx.x;
    const int lo = bbase[b], hi = bbase[b + 1];
    const int cnt = hi - lo;
    hist[t] = 0; cur[t] = 0;
    __syncthreads();
    for (int i = t; i < cnt; i += 256)
        atomicAdd(&hist[tmp[lo + i] & 255], 1);
    __syncthreads();
    int v = hist[t];
    ssc[t] = v;
    __syncthreads();
    for (int off = 1; off < 256; off <<= 1) {
        int a = (t >= off) ? ssc[t - off] : 0;
        __syncthreads();
        ssc[t] += a;
        __syncthreads();
    }
    pfx[t] = ssc[t] - v;
    const int node = b * 256 + t;
    if (node < N) rowptr[node] = lo + pfx[t];
    __syncthreads();
    if (cnt <= CAPC) {
        for (int i = t; i < cnt; i += 256) {
            int w = tmp[lo + i];
            int d = w & 255;
            int p = pfx[d] + atomicAdd(&cur[d], 1);
            sadj[p] = w >> 8;
        }
        __syncthreads();
        for (int i = t; i < cnt; i += 256) adj[lo + i] = sadj[i];
    } else {
        for (int i = t; i < cnt; i += 256) {
            int w = tmp[lo + i];
            int d = w & 255;
            int p = pfx[d] + atomicAdd(&cur[d], 1);
            adj[lo + p] = w >> 8;
        }
    }
}

// ========== aggregation: z[n] = h[n] + sum_{m in adj(n)} h[m], bf16 in/out ==========
// one wave per node, lane = feature; unroll 8 for 8 gathers in flight
__global__ __launch_bounds__(256) void aggregate_k(
    const bf16* __restrict__ h, const int* __restrict__ rowptr,
    const int* __restrict__ adj, bf16* __restrict__ z, int N)
{
    int n = blockIdx.x * 4 + (threadIdx.x >> 6);
    if (n >= N) return;
    const int f = threadIdx.x & 63;
    const int b = rowptr[n], e = rowptr[n + 1];
    float s = b2f(h[(size_t)n * 64 + f]);
    int i = b;
    for (; i + 8 <= e; i += 8) {
        int m0 = adj[i], m1 = adj[i + 1], m2 = adj[i + 2], m3 = adj[i + 3];
        int m4 = adj[i + 4], m5 = adj[i + 5], m6 = adj[i + 6], m7 = adj[i + 7];
        float v0 = b2f(h[(size_t)m0 * 64 + f]);
        float v1 = b2f(h[(size_t)m1 * 64 + f]);
        float v2 = b2f(h[(size_t)m2 * 64 + f]);
        float v3 = b2f(h[(size_t)m3 * 64 + f]);
        float v4 = b2f(h[(size_t)m4 * 64 + f]);
        float v5 = b2f(h[(size_t)m5 * 64 + f]);
        float v6 = b2f(h[(size_t)m6 * 64 + f]);
        float v7 = b2f(h[(size_t)m7 * 64 + f]);
        s += ((v0 + v1) + (v2 + v3)) + ((v4 + v5) + (v6 + v7));
    }
    for (; i + 2 <= e; i += 2) {
        int m0 = adj[i], m1 = adj[i + 1];
        s += b2f(h[(size_t)m0 * 64 + f]) + b2f(h[(size_t)m1 * 64 + f]);
    }
    if (i < e) s += b2f(h[(size_t)adj[i] * 64 + f]);
    z[(size_t)n * 64 + f] = f2b(s);
}

// ---------------- GEMM (bf16 in / bf16 out, f32 compute) + fused BN stats ----------------
// MODE 0: a = A;  MODE 1: a = relu(A*scale + shift). In-place safe (out==A).
template<int MODE>
__global__ __launch_bounds__(256) void gemm64_k(
    const bf16* __restrict__ A,
    const float* __restrict__ scale, const float* __restrict__ shift,
    const float* __restrict__ W, const float* __restrict__ bias,
    bf16* __restrict__ out, float* __restrict__ stats, int nrows)
{
    __shared__ float sW[64 * 68];
    __shared__ float sA[128 * 68];
    const int tid = threadIdx.x;

    for (int idx4 = tid; idx4 < 1024; idx4 += 256) {
        int r = idx4 >> 4, c4 = (idx4 & 15) * 4;
        *(float4*)(sW + r * 68 + c4) = *(const float4*)(W + idx4 * 4);
    }

    const int row0 = blockIdx.x * 128;
    const int rows = min(128, nrows - row0);

    for (int idx4 = tid; idx4 < rows * 16; idx4 += 256) {
        int r = idx4 >> 4, c4 = (idx4 & 15) * 4;
        union { ushort4 u; bf16 b[4]; } p;
        p.u = *(const ushort4*)(A + (size_t)(row0 + r) * 64 + c4);
        float4 v = make_float4(b2f(p.b[0]), b2f(p.b[1]), b2f(p.b[2]), b2f(p.b[3]));
        if (MODE == 1) {
            float4 sc = *(const float4*)(scale + c4);
            float4 sh = *(const float4*)(shift + c4);
            v.x = fmaxf(fmaf(v.x, sc.x, sh.x), 0.f);
            v.y = fmaxf(fmaf(v.y, sc.y, sh.y), 0.f);
            v.z = fmaxf(fmaf(v.z, sc.z, sh.z), 0.f);
            v.w = fmaxf(fmaf(v.w, sc.w, sh.w), 0.f);
        }
        *(float4*)(sA + r * 68 + c4) = v;
    }
    __syncthreads();

    const int cg = tid & 15, rg = tid >> 4;
    const int c0 = cg * 4;

    float acc[8][4];
    {
        float4 bv = *(const float4*)(bias + c0);
        #pragma unroll
        for (int i = 0; i < 8; i++) {
            acc[i][0] = bv.x; acc[i][1] = bv.y; acc[i][2] = bv.z; acc[i][3] = bv.w;
        }
    }

    #pragma unroll 2
    for (int k0 = 0; k0 < 64; k0 += 4) {
        float4 w0 = *(const float4*)(sW + (k0 + 0) * 68 + c0);
        float4 w1 = *(const float4*)(sW + (k0 + 1) * 68 + c0);
        float4 w2 = *(const float4*)(sW + (k0 + 2) * 68 + c0);
        float4 w3 = *(const float4*)(sW + (k0 + 3) * 68 + c0);
        #pragma unroll
        for (int i = 0; i < 8; i++) {
            float4 a = *(const float4*)(sA + (rg + 16 * i) * 68 + k0);
            acc[i][0] = fmaf(a.w, w3.x, fmaf(a.z, w2.x, fmaf(a.y, w1.x, fmaf(a.x, w0.x, acc[i][0]))));
            acc[i][1] = fmaf(a.w, w3.y, fmaf(a.z, w2.y, fmaf(a.y, w1.y, fmaf(a.x, w0.y, acc[i][1]))));
            acc[i][2] = fmaf(a.w, w3.z, fmaf(a.z, w2.z, fmaf(a.y, w1.z, fmaf(a.x, w0.z, acc[i][2]))));
            acc[i][3] = fmaf(a.w, w3.w, fmaf(a.z, w2.w, fmaf(a.y, w1.w, fmaf(a.x, w0.w, acc[i][3]))));
        }
    }

    float csum[4] = {0.f, 0.f, 0.f, 0.f}, csq[4] = {0.f, 0.f, 0.f, 0.f};
    #pragma unroll
    for (int i = 0; i < 8; i++) {
        int r = rg + 16 * i;
        if (r < rows) {
            union { ushort4 u; bf16 b[4]; } p;
            p.b[0] = f2b(acc[i][0]); p.b[1] = f2b(acc[i][1]);
            p.b[2] = f2b(acc[i][2]); p.b[3] = f2b(acc[i][3]);
            *(ushort4*)(out + (size_t)(row0 + r) * 64 + c0) = p.u;
            #pragma unroll
            for (int j = 0; j < 4; j++) {
                csum[j] += acc[i][j];
                csq[j] = fmaf(acc[i][j], acc[i][j], csq[j]);
            }
        }
    }

    __syncthreads();
    #pragma unroll
    for (int j = 0; j < 4; j++) {
        sA[rg * 64 + c0 + j] = csum[j];
        sA[1024 + rg * 64 + c0 + j] = csq[j];
    }
    __syncthreads();
    if (tid < 128) {
        const int c = tid & 63, which = tid >> 6;
        const float* p = sA + which * 1024 + c;
        float a = 0.f;
        #pragma unroll
        for (int g2 = 0; g2 < 16; g2++) a += p[g2 * 64];
        atomicAdd(&stats[which * 64 + c], a);
    }
}

__global__ __launch_bounds__(64) void bn_finalize_k(
    const float* __restrict__ stats, const float* __restrict__ g,
    const float* __restrict__ be, float* __restrict__ sc,
    float* __restrict__ sh, float invN)
{
    const int f = threadIdx.x;
    float m = stats[f] * invN;
    float v = stats[64 + f] * invN - m * m;
    float s = g[f] * rsqrtf(v + BN_EPS);
    sc[f] = s;
    sh[f] = be[f] - m * s;
}

// f32 -> bf16 cast
__global__ __launch_bounds__(256) void cast_k(
    const float* __restrict__ in, bf16* __restrict__ out, int total4)
{
    int i = blockIdx.x * 256 + threadIdx.x;
    if (i >= total4) return;
    float4 v = ((const float4*)in)[i];
    union { ushort4 u; bf16 b[4]; } p;
    p.b[0] = f2b(v.x); p.b[1] = f2b(v.y); p.b[2] = f2b(v.z); p.b[3] = f2b(v.w);
    ((ushort4*)out)[i] = p.u;
}

// relu(affine(z)) bf16 -> bf16
__global__ __launch_bounds__(256) void affine_relu_bf16_k(
    const bf16* __restrict__ in, const float* __restrict__ sc,
    const float* __restrict__ sh, bf16* __restrict__ out, int total4)
{
    int i = blockIdx.x * 256 + threadIdx.x;
    if (i >= total4) return;
    union { ushort4 u; bf16 b[4]; } q;
    q.u = ((const ushort4*)in)[i];
    int c4 = i & 15;
    float4 s = ((const float4*)sc)[c4];
    float4 t = ((const float4*)sh)[c4];
    union { ushort4 u; bf16 b[4]; } p;
    p.b[0] = f2b(fmaxf(fmaf(b2f(q.b[0]), s.x, t.x), 0.f));
    p.b[1] = f2b(fmaxf(fmaf(b2f(q.b[1]), s.y, t.y), 0.f));
    p.b[2] = f2b(fmaxf(fmaf(b2f(q.b[2]), s.z, t.z), 0.f));
    p.b[3] = f2b(fmaxf(fmaf(b2f(q.b[3]), s.w, t.w), 0.f));
    ((ushort4*)out)[i] = p.u;
}

// ---------------- pooled readout; h2 = relu(affine(z)) applied on the fly ----------------
__global__ __launch_bounds__(256) void pool_readout_k(
    const bf16* __restrict__ xb, const bf16* __restrict__ h1b,
    const bf16* __restrict__ z, const float* __restrict__ sc2,
    const float* __restrict__ sh2, const int* __restrict__ batch,
    const float* __restrict__ w0, const float* __restrict__ b0,
    const float* __restrict__ w1, const float* __restrict__ b1,
    const float* __restrict__ w2, const float* __restrict__ b2,
    float* __restrict__ out, int Nn)
{
    const int g = blockIdx.x;
    int lo = 0, hi = Nn;
    while (lo < hi) { int mid = (lo + hi) >> 1; if (batch[mid] < g) lo = mid + 1; else hi = mid; }
    const int start = lo;
    hi = Nn;
    while (lo < hi) { int mid = (lo + hi) >> 1; if (batch[mid] <= g) lo = mid + 1; else hi = mid; }
    const int end = lo;

    const int f = threadIdx.x & 63;
    const int w = threadIdx.x >> 6;
    const float scf = sc2[f], shf = sh2[f];
    float s0 = 0.f, s1 = 0.f, s2 = 0.f;
    for (int i = start + w; i < end; i += 4) {
        s0 += b2f(xb [(size_t)i * 64 + f]);
        s1 += b2f(h1b[(size_t)i * 64 + f]);
        s2 += fmaxf(fmaf(b2f(z[(size_t)i * 64 + f]), scf, shf), 0.f);
    }
    __shared__ float p[3][4][64];
    p[0][w][f] = s0; p[1][w][f] = s1; p[2][w][f] = s2;
    __syncthreads();
    if (threadIdx.x < 10) {
        const int c = threadIdx.x;
        float acc = b0[c] + b1[c] + b2[c];
        for (int k = 0; k < 64; k++) {
            float q0 = p[0][0][k] + p[0][1][k] + p[0][2][k] + p[0][3][k];
            float q1 = p[1][0][k] + p[1][1][k] + p[1][2][k] + p[1][3][k];
            float q2 = p[2][0][k] + p[2][1][k] + p[2][2][k] + p[2][3][k];
            acc = fmaf(q0, w0[k * 10 + c], acc);
            acc = fmaf(q1, w1[k * 10 + c], acc);
            acc = fmaf(q2, w2[k * 10 + c], acc);
        }
        out[(size_t)g * 10 + c] = acc;
    }
}

extern "C" void kernel_launch(void* const* d_in, const int* in_sizes, int n_in,
                              void* d_out, int out_size, void* d_ws, size_t ws_size,
                              hipStream_t stream)
{
    const float* x     = (const float*)d_in[0];
    const int*   edge  = (const int*)d_in[1];
    const int*   batch = (const int*)d_in[2];
    const int N = in_sizes[0] / 64;
    const int E = in_sizes[1] / 2;
    const int G = out_size / 10;
    const int* src = edge;
    const int* dst = edge + E;
    const int NB = (N + 255) / 256;

    const float* c_w1[2]  = {(const float*)d_in[3],  (const float*)d_in[11]};
    const float* c_b1[2]  = {(const float*)d_in[4],  (const float*)d_in[12]};
    const float* c_g1[2]  = {(const float*)d_in[5],  (const float*)d_in[13]};
    const float* c_be1[2] = {(const float*)d_in[6],  (const float*)d_in[14]};
    const float* c_w2[2]  = {(const float*)d_in[7],  (const float*)d_in[15]};
    const float* c_b2[2]  = {(const float*)d_in[8],  (const float*)d_in[16]};
    const float* bn_g[2]  = {(const float*)d_in[9],  (const float*)d_in[17]};
    const float* bn_b[2]  = {(const float*)d_in[10], (const float*)d_in[18]};
    const float* lw[3]    = {(const float*)d_in[19], (const float*)d_in[21], (const float*)d_in[23]};
    const float* lb[3]    = {(const float*)d_in[20], (const float*)d_in[22], (const float*)d_in[24]};

    float* out = (float*)d_out;
    const size_t nh = (size_t)N * 64;

    // workspace layout
    bf16*  zb    = (bf16*)d_ws;                // nh bf16 (agg/gemm in-place buffer)
    bf16*  xb    = zb + nh;                    // nh bf16
    bf16*  h1b   = xb + nh;                    // nh bf16
    float* stats = (float*)(h1b + nh);         // 4 slots x 128
    float* sc    = stats + 512;                // 64
    float* sh    = sc + 64;                    // 64
    int*   rowptr   = (int*)(sh + 64);         // N+1
    int*   adj      = rowptr + N + 1;          // E
    int*   tmp      = adj + E;                 // E
    int*   btot     = tmp + E;                 // NB+1
    int*   bbase    = btot + NB + 1;           // NB+1
    int*   bcur     = bbase + NB + 1;          // NB

    const float invN = 1.0f / (float)N;
    const int gemmGrid = (N + 127) / 128;
    const int binGrid  = (E + CHUNK - 1) / CHUNK;
    const int aggGrid  = (N + 3) / 4;
    const int ewGrid   = (int)((nh / 4 + 255) / 256);

    hipMemsetAsync(btot, 0, (size_t)(NB + 1) * sizeof(int), stream);
    hipMemsetAsync(stats, 0, 512 * sizeof(float), stream);

    // ---- CSR build ----
    bincount_k<<<binGrid, 256, 0, stream>>>(dst, btot, E, NB);
    bucketscan_k<<<1, 256, 0, stream>>>(btot, bbase, bcur, rowptr, NB, N, E);
    binscatter_k<<<binGrid, 256, 0, stream>>>(src, dst, bcur, tmp, E, NB);
    csr_k<<<NB, 256, 0, stream>>>(bbase, tmp, rowptr, adj, N);

    // ---- x -> bf16 ----
    cast_k<<<ewGrid, 256, 0, stream>>>(x, xb, (int)(nh / 4));

    // ---- layer 0 ----
    aggregate_k<<<aggGrid, 256, 0, stream>>>(xb, rowptr, adj, zb, N);
    gemm64_k<0><<<gemmGrid, 256, 0, stream>>>(zb, nullptr, nullptr,
                                              c_w1[0], c_b1[0], zb, stats, N);
    bn_finalize_k<<<1, 64, 0, stream>>>(stats, c_g1[0], c_be1[0], sc, sh, invN);
    gemm64_k<1><<<gemmGrid, 256, 0, stream>>>(zb, sc, sh,
                                              c_w2[0], c_b2[0], zb, stats + 128, N);
    bn_finalize_k<<<1, 64, 0, stream>>>(stats + 128, bn_g[0], bn_b[0], sc, sh, invN);
    affine_relu_bf16_k<<<ewGrid, 256, 0, stream>>>(zb, sc, sh, h1b, (int)(nh / 4));

    // ---- layer 1 ----
    aggregate_k<<<aggGrid, 256, 0, stream>>>(h1b, rowptr, adj, zb, N);
    gemm64_k<0><<<gemmGrid, 256, 0, stream>>>(zb, nullptr, nullptr,
                                              c_w1[1], c_b1[1], zb, stats + 256, N);
    bn_finalize_k<<<1, 64, 0, stream>>>(stats + 256, c_g1[1], c_be1[1], sc, sh, invN);
    gemm64_k<1><<<gemmGrid, 256, 0, stream>>>(zb, sc, sh,
                                              c_w2[1], c_b2[1], zb, stats + 384, N);
    bn_finalize_k<<<1, 64, 0, stream>>>(stats + 384, bn_g[1], bn_b[1], sc, sh, invN);

    // ---- pooled readout (h2 affine+relu fused) ----
    pool_readout_k<<<G, 256, 0, stream>>>(xb, h1b, zb, sc, sh, batch,
                                          lw[0], lb[0], lw[1], lb[1], lw[2], lb[2],
                                          out, N);
}

// Round 5
// 423.507 us; speedup vs baseline: 7.2773x; 1.0876x over previous
//
#include <hip/hip_runtime.h>
#include <hip/hip_bf16.h>

#define BN_EPS 1e-5f
#define NBMAX 512      // max buckets (N/256)
#define CHUNK 4096     // edges per binning block
#define CAPC  6144     // per-bucket LDS staging capacity (avg ~4096)

typedef __hip_bfloat16 bf16;

__device__ __forceinline__ float b2f(bf16 v) { return __bfloat162float(v); }
__device__ __forceinline__ bf16 f2b(float v) { return __float2bfloat16(v); }
__device__ __forceinline__ float bl(unsigned u) { return __uint_as_float(u << 16); }
__device__ __forceinline__ float bh(unsigned u) { return __uint_as_float(u & 0xffff0000u); }
__device__ __forceinline__ unsigned pack2(float x, float y) {
    union { bf16 b[2]; unsigned u; } p;
    p.b[0] = f2b(x); p.b[1] = f2b(y);
    return p.u;
}

// ================= init: zero btot + stats in one launch =================
__global__ __launch_bounds__(1024) void init_k(
    int* __restrict__ btot, float* __restrict__ stats, int nbp1)
{
    int t = threadIdx.x;
    if (t < nbp1) btot[t] = 0;
    if (t < 512) stats[t] = 0.f;
}

// ================= CSR build: two-level bucket sort over dst =================

__global__ __launch_bounds__(256) void bincount_k(
    const int* __restrict__ dst, int* __restrict__ btot, int E, int NB)
{
    __shared__ int h[NBMAX];
    for (int i = threadIdx.x; i < NB; i += 256) h[i] = 0;
    __syncthreads();
    const int base = blockIdx.x * CHUNK;
    const int lim = min(CHUNK, E - base);
    for (int i = threadIdx.x; i < lim; i += 256)
        atomicAdd(&h[dst[base + i] >> 8], 1);
    __syncthreads();
    for (int i = threadIdx.x; i < NB; i += 256)
        if (h[i]) atomicAdd(&btot[i], h[i]);
}

__global__ __launch_bounds__(256) void bucketscan_k(
    const int* __restrict__ btot, int* __restrict__ bbase,
    int* __restrict__ bcur, int* __restrict__ rowptr, int NB, int N, int E)
{
    __shared__ int s[256];
    const int t = threadIdx.x;
    int v0 = (2 * t     < NB) ? btot[2 * t]     : 0;
    int v1 = (2 * t + 1 < NB) ? btot[2 * t + 1] : 0;
    s[t] = v0 + v1;
    __syncthreads();
    for (int off = 1; off < 256; off <<= 1) {
        int a = (t >= off) ? s[t - off] : 0;
        __syncthreads();
        s[t] += a;
        __syncthreads();
    }
    int excl = s[t] - (v0 + v1);
    if (2 * t < NB)     { bbase[2 * t] = excl;          bcur[2 * t] = excl; }
    if (2 * t + 1 < NB) { bbase[2 * t + 1] = excl + v0; bcur[2 * t + 1] = excl + v0; }
    if (t == 0) { bbase[NB] = E; rowptr[N] = E; }
}

__global__ __launch_bounds__(256) void binscatter_k(
    const int* __restrict__ src, const int* __restrict__ dst,
    int* __restrict__ bcur, int* __restrict__ tmp, int E, int NB)
{
    __shared__ int hist[NBMAX];
    __shared__ int loff[NBMAX];
    __shared__ int gb[NBMAX];
    __shared__ int lcur[NBMAX];
    __shared__ int staged[CHUNK];
    __shared__ unsigned short sb[CHUNK];
    __shared__ int ssc[256];
    const int t = threadIdx.x;
    for (int i = t; i < NB; i += 256) { hist[i] = 0; lcur[i] = 0; }
    __syncthreads();
    const int base = blockIdx.x * CHUNK;
    const int lim = min(CHUNK, E - base);
    int myb[16], myw[16];
    int cnt = 0;
    for (int i = t; i < lim; i += 256) {
        int d = dst[base + i];
        int s_ = src[base + i];
        int b = d >> 8;
        myb[cnt] = b;
        myw[cnt] = (s_ << 8) | (d & 255);
        cnt++;
        atomicAdd(&hist[b], 1);
    }
    __syncthreads();
    int v0 = (2 * t     < NB) ? hist[2 * t]     : 0;
    int v1 = (2 * t + 1 < NB) ? hist[2 * t + 1] : 0;
    ssc[t] = v0 + v1;
    __syncthreads();
    for (int off = 1; off < 256; off <<= 1) {
        int a = (t >= off) ? ssc[t - off] : 0;
        __syncthreads();
        ssc[t] += a;
        __syncthreads();
    }
    int excl = ssc[t] - (v0 + v1);
    if (2 * t < NB)     loff[2 * t] = excl;
    if (2 * t + 1 < NB) loff[2 * t + 1] = excl + v0;
    __syncthreads();
    for (int b = t; b < NB; b += 256)
        if (hist[b] > 0) gb[b] = atomicAdd(&bcur[b], hist[b]);
    for (int i = 0; i < cnt; i++) {
        int b = myb[i];
        int p = loff[b] + atomicAdd(&lcur[b], 1);
        staged[p] = myw[i];
        sb[p] = (unsigned short)b;
    }
    __syncthreads();
    for (int i = t; i < lim; i += 256) {
        int b = sb[i];
        tmp[gb[b] + (i - loff[b])] = staged[i];
    }
}

__global__ __launch_bounds__(256) void csr_k(
    const int* __restrict__ bbase, const int* __restrict__ tmp,
    int* __restrict__ rowptr, int* __restrict__ adj, int N)
{
    __shared__ int hist[256], pfx[256], cur[256], ssc[256];
    __shared__ int sadj[CAPC];
    const int b = blockIdx.x, t = threadIdx.x;
    const int lo = bbase[b], hi = bbase[b + 1];
    const int cnt = hi - lo;
    hist[t] = 0; cur[t] = 0;
    __syncthreads();
    for (int i = t; i < cnt; i += 256)
        atomicAdd(&hist[tmp[lo + i] & 255], 1);
    __syncthreads();
    int v = hist[t];
    ssc[t] = v;
    __syncthreads();
    for (int off = 1; off < 256; off <<= 1) {
        int a = (t >= off) ? ssc[t - off] : 0;
        __syncthreads();
        ssc[t] += a;
        __syncthreads();
    }
    pfx[t] = ssc[t] - v;
    const int node = b * 256 + t;
    if (node < N) rowptr[node] = lo + pfx[t];
    __syncthreads();
    if (cnt <= CAPC) {
        for (int i = t; i < cnt; i += 256) {
            int w = tmp[lo + i];
            int d = w & 255;
            int p = pfx[d] + atomicAdd(&cur[d], 1);
            sadj[p] = w >> 8;
        }
        __syncthreads();
        for (int i = t; i < cnt; i += 256) adj[lo + i] = sadj[i];
    } else {
        for (int i = t; i < cnt; i += 256) {
            int w = tmp[lo + i];
            int d = w & 255;
            int p = pfx[d] + atomicAdd(&cur[d], 1);
            adj[lo + p] = w >> 8;
        }
    }
}

// ========== aggregation: z[n] = act(h[n]) + sum_m act(h[m]) ==========
// half-wave per node: lane carries feature pair (2*lane, 2*lane+1) via 4B load
// -> one wave-load fetches 2 rows; unroll 8 -> 16 rows in flight per wave.
// AFFINE=1: act(v) = relu(v*scale+shift) computed inline from raw BN stats.
template<int AFFINE>
__global__ __launch_bounds__(256) void aggregate_k(
    const bf16* __restrict__ h, const int* __restrict__ rowptr,
    const int* __restrict__ adj, bf16* __restrict__ z, int N,
    const float* __restrict__ stats, const float* __restrict__ g,
    const float* __restrict__ be, float invN)
{
    const int lane = threadIdx.x & 31;
    const int n = blockIdx.x * 8 + (threadIdx.x >> 5);
    float sc0 = 0.f, sc1 = 0.f, sh0 = 0.f, sh1 = 0.f;
    if (AFFINE) {
        const int f0 = lane * 2, f1 = f0 + 1;
        float m0 = stats[f0] * invN;
        float va0 = stats[64 + f0] * invN - m0 * m0;
        float s0_ = g[f0] * rsqrtf(va0 + BN_EPS);
        sc0 = s0_; sh0 = be[f0] - m0 * s0_;
        float m1 = stats[f1] * invN;
        float va1 = stats[64 + f1] * invN - m1 * m1;
        float s1_ = g[f1] * rsqrtf(va1 + BN_EPS);
        sc1 = s1_; sh1 = be[f1] - m1 * s1_;
    }
    if (n >= N) return;
    const unsigned* hp = (const unsigned*)h;   // bf16x2 words, row stride 32
    const int b = rowptr[n], e = rowptr[n + 1];

    unsigned u = hp[(size_t)n * 32 + lane];
    float a0 = bl(u), a1 = bh(u);
    if (AFFINE) {
        a0 = fmaxf(fmaf(a0, sc0, sh0), 0.f);
        a1 = fmaxf(fmaf(a1, sc1, sh1), 0.f);
    }
    float s0 = a0, s1 = a1;

    int i = b;
    for (; i + 8 <= e; i += 8) {
        int m[8];
        #pragma unroll
        for (int k = 0; k < 8; k++) m[k] = adj[i + k];
        unsigned w[8];
        #pragma unroll
        for (int k = 0; k < 8; k++) w[k] = hp[(size_t)m[k] * 32 + lane];
        #pragma unroll
        for (int k = 0; k < 8; k++) {
            float p0 = bl(w[k]), p1 = bh(w[k]);
            if (AFFINE) {
                p0 = fmaxf(fmaf(p0, sc0, sh0), 0.f);
                p1 = fmaxf(fmaf(p1, sc1, sh1), 0.f);
            }
            s0 += p0; s1 += p1;
        }
    }
    for (; i < e; i++) {
        unsigned w = hp[(size_t)adj[i] * 32 + lane];
        float p0 = bl(w), p1 = bh(w);
        if (AFFINE) {
            p0 = fmaxf(fmaf(p0, sc0, sh0), 0.f);
            p1 = fmaxf(fmaf(p1, sc1, sh1), 0.f);
        }
        s0 += p0; s1 += p1;
    }
    ((unsigned*)z)[(size_t)n * 32 + lane] = pack2(s0, s1);
}

// ---------------- GEMM (bf16 in/out, f32 compute) + fused BN ----------------
// MODE 0: a = A;  MODE 1: a = relu(A*scale+shift), scale/shift computed inline
// from raw stats_in + g + be. Writes raw col sums/sumsq to stats_out.
// In-place safe (out==A).
template<int MODE>
__global__ __launch_bounds__(256) void gemm64_k(
    const bf16* __restrict__ A,
    const float* __restrict__ stats_in, const float* __restrict__ g,
    const float* __restrict__ be, float invN,
    const float* __restrict__ W, const float* __restrict__ bias,
    bf16* __restrict__ out, float* __restrict__ stats_out, int nrows)
{
    __shared__ float sW[64 * 68];
    __shared__ float sA[128 * 68];
    __shared__ float sSc[64], sSh[64];
    const int tid = threadIdx.x;

    if (MODE == 1 && tid < 64) {
        float m = stats_in[tid] * invN;
        float v = stats_in[64 + tid] * invN - m * m;
        float s = g[tid] * rsqrtf(v + BN_EPS);
        sSc[tid] = s;
        sSh[tid] = be[tid] - m * s;
    }

    for (int idx4 = tid; idx4 < 1024; idx4 += 256) {
        int r = idx4 >> 4, c4 = (idx4 & 15) * 4;
        *(float4*)(sW + r * 68 + c4) = *(const float4*)(W + idx4 * 4);
    }
    __syncthreads();

    const int row0 = blockIdx.x * 128;
    const int rows = min(128, nrows - row0);

    for (int idx4 = tid; idx4 < rows * 16; idx4 += 256) {
        int r = idx4 >> 4, c4 = (idx4 & 15) * 4;
        union { ushort4 u; bf16 b[4]; } p;
        p.u = *(const ushort4*)(A + (size_t)(row0 + r) * 64 + c4);
        float4 v = make_float4(b2f(p.b[0]), b2f(p.b[1]), b2f(p.b[2]), b2f(p.b[3]));
        if (MODE == 1) {
            float4 sc = *(const float4*)(sSc + c4);
            float4 sh = *(const float4*)(sSh + c4);
            v.x = fmaxf(fmaf(v.x, sc.x, sh.x), 0.f);
            v.y = fmaxf(fmaf(v.y, sc.y, sh.y), 0.f);
            v.z = fmaxf(fmaf(v.z, sc.z, sh.z), 0.f);
            v.w = fmaxf(fmaf(v.w, sc.w, sh.w), 0.f);
        }
        *(float4*)(sA + r * 68 + c4) = v;
    }
    __syncthreads();

    const int cg = tid & 15, rg = tid >> 4;
    const int c0 = cg * 4;

    float acc[8][4];
    {
        float4 bv = *(const float4*)(bias + c0);
        #pragma unroll
        for (int i = 0; i < 8; i++) {
            acc[i][0] = bv.x; acc[i][1] = bv.y; acc[i][2] = bv.z; acc[i][3] = bv.w;
        }
    }

    #pragma unroll 2
    for (int k0 = 0; k0 < 64; k0 += 4) {
        float4 w0 = *(const float4*)(sW + (k0 + 0) * 68 + c0);
        float4 w1 = *(const float4*)(sW + (k0 + 1) * 68 + c0);
        float4 w2 = *(const float4*)(sW + (k0 + 2) * 68 + c0);
        float4 w3 = *(const float4*)(sW + (k0 + 3) * 68 + c0);
        #pragma unroll
        for (int i = 0; i < 8; i++) {
            float4 a = *(const float4*)(sA + (rg + 16 * i) * 68 + k0);
            acc[i][0] = fmaf(a.w, w3.x, fmaf(a.z, w2.x, fmaf(a.y, w1.x, fmaf(a.x, w0.x, acc[i][0]))));
            acc[i][1] = fmaf(a.w, w3.y, fmaf(a.z, w2.y, fmaf(a.y, w1.y, fmaf(a.x, w0.y, acc[i][1]))));
            acc[i][2] = fmaf(a.w, w3.z, fmaf(a.z, w2.z, fmaf(a.y, w1.z, fmaf(a.x, w0.z, acc[i][2]))));
            acc[i][3] = fmaf(a.w, w3.w, fmaf(a.z, w2.w, fmaf(a.y, w1.w, fmaf(a.x, w0.w, acc[i][3]))));
        }
    }

    float csum[4] = {0.f, 0.f, 0.f, 0.f}, csq[4] = {0.f, 0.f, 0.f, 0.f};
    #pragma unroll
    for (int i = 0; i < 8; i++) {
        int r = rg + 16 * i;
        if (r < rows) {
            union { ushort4 u; bf16 b[4]; } p;
            p.b[0] = f2b(acc[i][0]); p.b[1] = f2b(acc[i][1]);
            p.b[2] = f2b(acc[i][2]); p.b[3] = f2b(acc[i][3]);
            *(ushort4*)(out + (size_t)(row0 + r) * 64 + c0) = p.u;
            #pragma unroll
            for (int j = 0; j < 4; j++) {
                csum[j] += acc[i][j];
                csq[j] = fmaf(acc[i][j], acc[i][j], csq[j]);
            }
        }
    }

    __syncthreads();
    #pragma unroll
    for (int j = 0; j < 4; j++) {
        sA[rg * 64 + c0 + j] = csum[j];
        sA[1024 + rg * 64 + c0 + j] = csq[j];
    }
    __syncthreads();
    if (tid < 128) {
        const int c = tid & 63, which = tid >> 6;
        const float* p = sA + which * 1024 + c;
        float a = 0.f;
        #pragma unroll
        for (int g2 = 0; g2 < 16; g2++) a += p[g2 * 64];
        atomicAdd(&stats_out[which * 64 + c], a);
    }
}

// f32 -> bf16 cast
__global__ __launch_bounds__(256) void cast_k(
    const float* __restrict__ in, bf16* __restrict__ out, int total4)
{
    int i = blockIdx.x * 256 + threadIdx.x;
    if (i >= total4) return;
    float4 v = ((const float4*)in)[i];
    union { ushort4 u; bf16 b[4]; } p;
    p.b[0] = f2b(v.x); p.b[1] = f2b(v.y); p.b[2] = f2b(v.z); p.b[3] = f2b(v.w);
    ((ushort4*)out)[i] = p.u;
}

// ---------------- pooled readout; h1/h2 affine+relu applied on the fly ----------------
__global__ __launch_bounds__(256) void pool_readout_k(
    const bf16* __restrict__ xb, const bf16* __restrict__ z0,
    const bf16* __restrict__ z1, const int* __restrict__ batch,
    const float* __restrict__ st0, const float* __restrict__ g0,
    const float* __restrict__ be0,
    const float* __restrict__ st1, const float* __restrict__ g1,
    const float* __restrict__ be1, float invN,
    const float* __restrict__ w0, const float* __restrict__ b0,
    const float* __restrict__ w1, const float* __restrict__ b1,
    const float* __restrict__ w2, const float* __restrict__ b2,
    float* __restrict__ out, int Nn)
{
    const int g = blockIdx.x;
    int lo = 0, hi = Nn;
    while (lo < hi) { int mid = (lo + hi) >> 1; if (batch[mid] < g) lo = mid + 1; else hi = mid; }
    const int start = lo;
    hi = Nn;
    while (lo < hi) { int mid = (lo + hi) >> 1; if (batch[mid] <= g) lo = mid + 1; else hi = mid; }
    const int end = lo;

    const int f = threadIdx.x & 63;
    const int w = threadIdx.x >> 6;
    float m0_ = st0[f] * invN;
    float v0_ = st0[64 + f] * invN - m0_ * m0_;
    float sA = g0[f] * rsqrtf(v0_ + BN_EPS);
    float tA = be0[f] - m0_ * sA;
    float m1_ = st1[f] * invN;
    float v1_ = st1[64 + f] * invN - m1_ * m1_;
    float sB = g1[f] * rsqrtf(v1_ + BN_EPS);
    float tB = be1[f] - m1_ * sB;

    float s0 = 0.f, s1 = 0.f, s2 = 0.f;
    for (int i = start + w; i < end; i += 4) {
        s0 += b2f(xb[(size_t)i * 64 + f]);
        s1 += fmaxf(fmaf(b2f(z0[(size_t)i * 64 + f]), sA, tA), 0.f);
        s2 += fmaxf(fmaf(b2f(z1[(size_t)i * 64 + f]), sB, tB), 0.f);
    }
    __shared__ float p[3][4][64];
    p[0][w][f] = s0; p[1][w][f] = s1; p[2][w][f] = s2;
    __syncthreads();
    if (threadIdx.x < 10) {
        const int c = threadIdx.x;
        float acc = b0[c] + b1[c] + b2[c];
        for (int k = 0; k < 64; k++) {
            float q0 = p[0][0][k] + p[0][1][k] + p[0][2][k] + p[0][3][k];
            float q1 = p[1][0][k] + p[1][1][k] + p[1][2][k] + p[1][3][k];
            float q2 = p[2][0][k] + p[2][1][k] + p[2][2][k] + p[2][3][k];
            acc = fmaf(q0, w0[k * 10 + c], acc);
            acc = fmaf(q1, w1[k * 10 + c], acc);
            acc = fmaf(q2, w2[k * 10 + c], acc);
        }
        out[(size_t)g * 10 + c] = acc;
    }
}

extern "C" void kernel_launch(void* const* d_in, const int* in_sizes, int n_in,
                              void* d_out, int out_size, void* d_ws, size_t ws_size,
                              hipStream_t stream)
{
    const float* x     = (const float*)d_in[0];
    const int*   edge  = (const int*)d_in[1];
    const int*   batch = (const int*)d_in[2];
    const int N = in_sizes[0] / 64;
    const int E = in_sizes[1] / 2;
    const int G = out_size / 10;
    const int* src = edge;
    const int* dst = edge + E;
    const int NB = (N + 255) / 256;

    const float* c_w1[2]  = {(const float*)d_in[3],  (const float*)d_in[11]};
    const float* c_b1[2]  = {(const float*)d_in[4],  (const float*)d_in[12]};
    const float* c_g1[2]  = {(const float*)d_in[5],  (const float*)d_in[13]};
    const float* c_be1[2] = {(const float*)d_in[6],  (const float*)d_in[14]};
    const float* c_w2[2]  = {(const float*)d_in[7],  (const float*)d_in[15]};
    const float* c_b2[2]  = {(const float*)d_in[8],  (const float*)d_in[16]};
    const float* bn_g[2]  = {(const float*)d_in[9],  (const float*)d_in[17]};
    const float* bn_b[2]  = {(const float*)d_in[10], (const float*)d_in[18]};
    const float* lw[3]    = {(const float*)d_in[19], (const float*)d_in[21], (const float*)d_in[23]};
    const float* lb[3]    = {(const float*)d_in[20], (const float*)d_in[22], (const float*)d_in[24]};

    float* out = (float*)d_out;
    const size_t nh = (size_t)N * 64;

    // workspace layout
    bf16*  zb    = (bf16*)d_ws;                // nh bf16 (L0 agg/gemm buffer -> z0)
    bf16*  wb    = zb + nh;                    // nh bf16 (L1 agg/gemm buffer -> z1)
    bf16*  xb    = wb + nh;                    // nh bf16
    float* stats = (float*)(xb + nh);          // 4 slots x 128
    int*   rowptr   = (int*)(stats + 512);     // N+1
    int*   adj      = rowptr + N + 1;          // E
    int*   tmp      = adj + E;                 // E
    int*   btot     = tmp + E;                 // NB+1
    int*   bbase    = btot + NB + 1;           // NB+1
    int*   bcur     = bbase + NB + 1;          // NB

    const float invN = 1.0f / (float)N;
    const int gemmGrid = (N + 127) / 128;
    const int binGrid  = (E + CHUNK - 1) / CHUNK;
    const int aggGrid  = (N + 7) / 8;
    const int ewGrid   = (int)((nh / 4 + 255) / 256);

    // ---- init + CSR build ----
    init_k<<<1, 1024, 0, stream>>>(btot, stats, NB + 1);
    bincount_k<<<binGrid, 256, 0, stream>>>(dst, btot, E, NB);
    bucketscan_k<<<1, 256, 0, stream>>>(btot, bbase, bcur, rowptr, NB, N, E);
    binscatter_k<<<binGrid, 256, 0, stream>>>(src, dst, bcur, tmp, E, NB);
    csr_k<<<NB, 256, 0, stream>>>(bbase, tmp, rowptr, adj, N);

    // ---- x -> bf16 ----
    cast_k<<<ewGrid, 256, 0, stream>>>(x, xb, (int)(nh / 4));

    // ---- layer 0 ----
    aggregate_k<0><<<aggGrid, 256, 0, stream>>>(xb, rowptr, adj, zb, N,
                                                nullptr, nullptr, nullptr, 0.f);
    gemm64_k<0><<<gemmGrid, 256, 0, stream>>>(zb, nullptr, nullptr, nullptr, 0.f,
                                              c_w1[0], c_b1[0], zb, stats, N);
    gemm64_k<1><<<gemmGrid, 256, 0, stream>>>(zb, stats, c_g1[0], c_be1[0], invN,
                                              c_w2[0], c_b2[0], zb, stats + 128, N);

    // ---- layer 1 (h1 = relu(affine(z0)) applied inside aggregate) ----
    aggregate_k<1><<<aggGrid, 256, 0, stream>>>(zb, rowptr, adj, wb, N,
                                                stats + 128, bn_g[0], bn_b[0], invN);
    gemm64_k<0><<<gemmGrid, 256, 0, stream>>>(wb, nullptr, nullptr, nullptr, 0.f,
                                              c_w1[1], c_b1[1], wb, stats + 256, N);
    gemm64_k<1><<<gemmGrid, 256, 0, stream>>>(wb, stats + 256, c_g1[1], c_be1[1], invN,
                                              c_w2[1], c_b2[1], wb, stats + 384, N);

    // ---- pooled readout (h1/h2 affine+relu fused) ----
    pool_readout_k<<<G, 256, 0, stream>>>(xb, zb, wb, batch,
                                          stats + 128, bn_g[0], bn_b[0],
                                          stats + 384, bn_g[1], bn_b[1], invN,
                                          lw[0], lb[0], lw[1], lb[1], lw[2], lb[2],
                                          out, N);
}